// Round 26
// baseline (156.499 us; speedup 1.0000x reference)
//
#include <hip/hip_runtime.h>
#include <hip/hip_bf16.h>
#include <math.h>

#define EPS 1e-8f

typedef __attribute__((ext_vector_type(8))) short short8v;
typedef __attribute__((ext_vector_type(4))) float f32x4;

// ---------- helpers ----------
__device__ __forceinline__ unsigned fenc(float f) {
    unsigned u = __float_as_uint(f);
    return (u & 0x80000000u) ? ~u : (u | 0x80000000u);
}
__device__ __forceinline__ float fdec(unsigned e) {
    unsigned u = (e & 0x80000000u) ? (e & 0x7FFFFFFFu) : ~e;
    return __uint_as_float(u);
}
__device__ __forceinline__ unsigned short f2bf(float f) {   // RNE f32 -> bf16
    unsigned u = __float_as_uint(f);
    u += 0x7FFFu + ((u >> 16) & 1u);
    return (unsigned short)(u >> 16);
}

__device__ __forceinline__ float block_sum(float v, float* red) {
    red[threadIdx.x] = v;
    __syncthreads();
    for (int k = 128; k > 0; k >>= 1) {
        if (threadIdx.x < k) red[threadIdx.x] += red[threadIdx.x + k];
        __syncthreads();
    }
    float r = red[0];
    __syncthreads();
    return r;
}

// ---------- kernels ----------
__global__ void k_ghist(const int* tgt, int* gh, int B) {
    __shared__ int lh[1024];
    int g = blockIdx.x, t = threadIdx.x;
    lh[t] = 0; lh[t + 256] = 0; lh[t + 512] = 0; lh[t + 768] = 0;
    __syncthreads();
    int i = g * 256 + t;
    if (i < B) atomicAdd(&lh[tgt[i]], 1);
    __syncthreads();
    int* dst = gh + g * 1024;
    dst[t] = lh[t]; dst[t + 256] = lh[t + 256];
    dst[t + 512] = lh[t + 512]; dst[t + 768] = lh[t + 768];
}

__global__ void k_bases(int* gh, int* counts, int* offsets, unsigned* minmax, int G, int C) {
    __shared__ int buf[1024];
    int c = threadIdx.x;
    if (c == 0) { minmax[0] = 0xFFFFFFFFu; minmax[1] = 0u; }
    int run = 0;
#pragma unroll 16
    for (int g = 0; g < G; g++) {
        int v = gh[g * 1024 + c];
        gh[g * 1024 + c] = run;
        run += v;
    }
    if (c < C) counts[c] = run;
    int v0 = (c < C) ? run : 0;
    buf[c] = v0;
    __syncthreads();
    for (int off = 1; off < 1024; off <<= 1) {
        int v = (c >= off) ? buf[c - off] : 0;
        __syncthreads();
        buf[c] += v;
        __syncthreads();
    }
    if (c < C) offsets[c] = buf[c] - v0;
}

__global__ void k_rank_scatter(const int* tgt, const int* offsets, const int* gh,
                               int* idx, int B) {
    __shared__ int lt[256];
    int g = blockIdx.x, t = threadIdx.x;
    int i = g * 256 + t;
    int my = (i < B) ? tgt[i] : -1;
    lt[t] = my;
    __syncthreads();
    if (i < B) {
        int rank = 0;
        for (int j = 0; j < t; j++) rank += (lt[j] == my);
        idx[offsets[my] + gh[g * 1024 + my] + rank] = i;
    }
}

// FUSED table build: blocks [0,C) -> feature table + norms; blocks [C,2C) -> logit table.
// Register-resident indices + __shfl broadcast; unconditional float4 loads, x4 unroll,
// ascending accumulation order (deterministic).
__global__ __launch_bounds__(256) void k_tables(const float* feat, const float* finit,
                                                const float* logits, const float* linit,
                                                const int* counts, const int* offsets,
                                                const int* idx,
                                                float* ftab, float* ltab, float* norms,
                                                int C, int D, int C2) {
    __shared__ float red[256];
    int t = threadIdx.x;
    int lane = t & 63;
    if ((int)blockIdx.x < C) {
        int c = blockIdx.x;
        int n = counts[c];
        float o0, o1, o2, o3;
        if (n == 0) {
            float4 v = ((const float4*)(finit + (long)c * D))[t];
            o0 = v.x; o1 = v.y; o2 = v.z; o3 = v.w;
        } else {
            const float4* base4 = (const float4*)feat;
            int rowq = D >> 2;
            int o = offsets[c];
            float4 acc = {0.f, 0.f, 0.f, 0.f};
            for (int base = 0; base < n; base += 64) {
                int m = min(64, n - base);
                int lid = idx[o + base + min(lane, m - 1)];
                int m4 = m & ~3;
                int j = 0;
                for (; j < m4; j += 4) {
                    int i0 = __shfl(lid, j);
                    int i1 = __shfl(lid, j + 1);
                    int i2 = __shfl(lid, j + 2);
                    int i3 = __shfl(lid, j + 3);
                    float4 v0 = base4[(long)i0 * rowq + t];
                    float4 v1 = base4[(long)i1 * rowq + t];
                    float4 v2 = base4[(long)i2 * rowq + t];
                    float4 v3 = base4[(long)i3 * rowq + t];
                    acc.x += v0.x; acc.y += v0.y; acc.z += v0.z; acc.w += v0.w;
                    acc.x += v1.x; acc.y += v1.y; acc.z += v1.z; acc.w += v1.w;
                    acc.x += v2.x; acc.y += v2.y; acc.z += v2.z; acc.w += v2.w;
                    acc.x += v3.x; acc.y += v3.y; acc.z += v3.z; acc.w += v3.w;
                }
                for (; j < m; j++) {
                    int i0 = __shfl(lid, j);
                    float4 v0 = base4[(long)i0 * rowq + t];
                    acc.x += v0.x; acc.y += v0.y; acc.z += v0.z; acc.w += v0.w;
                }
            }
            float inv = 1.0f / (float)n;
            o0 = acc.x * inv; o1 = acc.y * inv; o2 = acc.z * inv; o3 = acc.w * inv;
        }
        float* dst = ftab + (long)c * D + t * 4;
        dst[0] = o0; dst[1] = o1; dst[2] = o2; dst[3] = o3;
        float ss = o0 * o0 + o1 * o1 + o2 * o2 + o3 * o3;
        ss = block_sum(ss, red);
        if (t == 0) norms[c] = sqrtf(ss);
    } else {
        int c = blockIdx.x - C;
        int n = counts[c];
        int nv = C2 >> 2;                           // 250
        if (n == 0) {
            for (int d = t; d < C2; d += 256) ltab[(long)c * C2 + d] = linit[(long)c * C2 + d];
            return;
        }
        int tc = min(t, nv - 1);                    // clamped -> unconditional loads
        int o = offsets[c];
        float4 acc = {0.f, 0.f, 0.f, 0.f};
        for (int base = 0; base < n; base += 64) {
            int m = min(64, n - base);
            int lid = idx[o + base + min(lane, m - 1)];
            int m4 = m & ~3;
            int j = 0;
            for (; j < m4; j += 4) {
                int i0 = __shfl(lid, j);
                int i1 = __shfl(lid, j + 1);
                int i2 = __shfl(lid, j + 2);
                int i3 = __shfl(lid, j + 3);
                float4 v0 = *(const float4*)(logits + (long)i0 * C2 + tc * 4);
                float4 v1 = *(const float4*)(logits + (long)i1 * C2 + tc * 4);
                float4 v2 = *(const float4*)(logits + (long)i2 * C2 + tc * 4);
                float4 v3 = *(const float4*)(logits + (long)i3 * C2 + tc * 4);
                acc.x += v0.x; acc.y += v0.y; acc.z += v0.z; acc.w += v0.w;
                acc.x += v1.x; acc.y += v1.y; acc.z += v1.z; acc.w += v1.w;
                acc.x += v2.x; acc.y += v2.y; acc.z += v2.z; acc.w += v2.w;
                acc.x += v3.x; acc.y += v3.y; acc.z += v3.z; acc.w += v3.w;
            }
            for (; j < m; j++) {
                int i0 = __shfl(lid, j);
                float4 v0 = *(const float4*)(logits + (long)i0 * C2 + tc * 4);
                acc.x += v0.x; acc.y += v0.y; acc.z += v0.z; acc.w += v0.w;
            }
        }
        if (t < nv) {
            float inv = 1.0f / (float)n;
            float* dst = ltab + (long)c * C2 + t * 4;
            dst[0] = acc.x * inv;
            dst[1] = acc.y * inv;
            dst[2] = acc.z * inv;
            dst[3] = acc.w * inv;
        }
    }
}

// FUSED: blocks [0,NTRI) = bf16-MFMA triangular GEMM tile (needs ftab);
// blocks [NTRI,..) = KL loss, 16 samples/block (needs ltab). GEMM hides under KL.
__global__ __launch_bounds__(1024) void k_gemm_kl(const float* A, float* S,
                                                  const float* logits, const float* LT,
                                                  const int* tgt, float* klpart,
                                                  int C, int D, int NT, int NTRI, int C2) {
    __shared__ __align__(16) unsigned short As[2][64][40];
    __shared__ __align__(16) unsigned short Bs[2][64][40];
    __shared__ __align__(16) float racc[64 * 68];
    int t = threadIdx.x;

    if ((int)blockIdx.x >= NTRI) {
        // ---------------- KL path: 16 waves, one sample each ----------------
        int wid = t >> 6, lane = t & 63;
        int s = ((int)blockIdx.x - NTRI) * 16 + wid;
        int cls = tgt[s];
        const float2* a2 = (const float2*)(LT + (long)cls * C2);     // 8B-aligned
        const float4* b4 = (const float4*)(logits + (long)s * C2);   // 16B-aligned
        int Q = C2 >> 2;   // 250
        float ta[16], tb[16];
        float m1 = -INFINITY, m2 = -INFINITY;
#pragma unroll
        for (int p = 0; p < 4; p++) {
            int j = lane + (p << 6);
            if (j < Q) {
                float4 vb = b4[j];
                float2 va0 = a2[2 * j], va1 = a2[2 * j + 1];
                ta[4 * p] = va0.x; ta[4 * p + 1] = va0.y;
                ta[4 * p + 2] = va1.x; ta[4 * p + 3] = va1.y;
                tb[4 * p] = vb.x; tb[4 * p + 1] = vb.y;
                tb[4 * p + 2] = vb.z; tb[4 * p + 3] = vb.w;
                m1 = fmaxf(m1, fmaxf(fmaxf(va0.x, va0.y), fmaxf(va1.x, va1.y)));
                m2 = fmaxf(m2, fmaxf(fmaxf(vb.x, vb.y), fmaxf(vb.z, vb.w)));
            } else {
#pragma unroll
                for (int r = 0; r < 4; r++) { ta[4 * p + r] = -INFINITY; tb[4 * p + r] = -INFINITY; }
            }
        }
#pragma unroll
        for (int o = 32; o > 0; o >>= 1) {
            m1 = fmaxf(m1, __shfl_xor(m1, o));
            m2 = fmaxf(m2, __shfl_xor(m2, o));
        }
        float e1[16];
        float s1 = 0.f, s2 = 0.f;
#pragma unroll
        for (int i = 0; i < 16; i++) {
            int j = lane + ((i >> 2) << 6);
            if (j < Q) {
                e1[i] = __expf(ta[i] - m1);
                s1 += e1[i];
                s2 += __expf(tb[i] - m2);
            } else {
                e1[i] = 0.f;
            }
        }
#pragma unroll
        for (int o = 32; o > 0; o >>= 1) {
            s1 += __shfl_xor(s1, o);
            s2 += __shfl_xor(s2, o);
        }
        float ls1 = __logf(s1), ls2 = __logf(s2);
        float inv = 1.f / s1;
        float kl = 0.f;
#pragma unroll
        for (int i = 0; i < 16; i++) {
            int j = lane + ((i >> 2) << 6);
            if (j < Q) {
                float lp = ta[i] - m1 - ls1;
                float lq = tb[i] - m2 - ls2;
                kl += e1[i] * inv * (lp - lq);
            }
        }
#pragma unroll
        for (int o = 32; o > 0; o >>= 1) kl += __shfl_xor(kl, o);
        if (lane == 0) klpart[s] = kl;
        return;
    }

    // ---------------- GEMM tile path (bf16 MFMA) ----------------
    int q = blockIdx.x, ti = 0;
    while (q >= NT - ti) { q -= NT - ti; ti++; }
    int tj = ti + q;
    int rb = ti * 64, cb = tj * 64;

    int srow = t >> 4;
    int skq = (t & 15) * 2;
    int ga = rb + srow, gb = cb + srow;
    bool okA = ga < C, okB = gb < C;
    const float* arow = A + (long)ga * D;
    const float* brow = A + (long)gb * D;

    int w = t >> 6, wr = w >> 2, wc = w & 3;
    int l = t & 63, fr = l & 15, fb = l >> 4;
    int arl = wr * 16 + fr, brl = wc * 16 + fr, koff = fb * 8;

    {
        float2 z2 = {0.f, 0.f};
        float2 pa = okA ? *(const float2*)(arow + skq) : z2;
        float2 pb = okB ? *(const float2*)(brow + skq) : z2;
        As[0][srow][skq] = f2bf(pa.x); As[0][srow][skq + 1] = f2bf(pa.y);
        Bs[0][srow][skq] = f2bf(pb.x); Bs[0][srow][skq + 1] = f2bf(pb.y);
    }
    __syncthreads();

    f32x4 acc = {0.f, 0.f, 0.f, 0.f};
    int nsteps = D >> 5;               // 32
    for (int step = 0; step < nsteps; step++) {
        int cur = step & 1;
        float2 pa, pb;
        if (step < nsteps - 1) {
            int k0n = (step + 1) * 32;
            float2 z2 = {0.f, 0.f};
            pa = okA ? *(const float2*)(arow + k0n + skq) : z2;
            pb = okB ? *(const float2*)(brow + k0n + skq) : z2;
        }
        short8v af = *reinterpret_cast<const short8v*>(&As[cur][arl][koff]);
        short8v bf = *reinterpret_cast<const short8v*>(&Bs[cur][brl][koff]);
        acc = __builtin_amdgcn_mfma_f32_16x16x32_bf16(af, bf, acc, 0, 0, 0);
        if (step < nsteps - 1) {
            int nb = cur ^ 1;
            As[nb][srow][skq] = f2bf(pa.x); As[nb][srow][skq + 1] = f2bf(pa.y);
            Bs[nb][srow][skq] = f2bf(pb.x); Bs[nb][srow][skq + 1] = f2bf(pb.y);
        }
        __syncthreads();
    }

#pragma unroll
    for (int r = 0; r < 4; r++)
        racc[(wr * 16 + fb * 4 + r) * 68 + wc * 16 + fr] = acc[r];
    __syncthreads();

    int r0 = t >> 4;
    int cbl = (t & 15) * 4;
    int gr = rb + r0;
    bool edge = (tj == NT - 1);
    if (gr < C) {
        float4 v4 = *reinterpret_cast<const float4*>(&racc[r0 * 68 + cbl]);
        float v[4] = {v4.x, v4.y, v4.z, v4.w};
        float* dst = S + (long)gr * C + cb + cbl;
        if (!edge) {
            *reinterpret_cast<float2*>(dst) = make_float2(v[0], v[1]);
            *reinterpret_cast<float2*>(dst + 2) = make_float2(v[2], v[3]);
        } else {
#pragma unroll
            for (int m = 0; m < 4; m++)
                if (cb + cbl + m < C) dst[m] = v[m];
        }
    }
    if (ti != tj) {
        int cc0 = cb + r0;
        if (cc0 < C) {
            float wv[4];
#pragma unroll
            for (int m = 0; m < 4; m++) wv[m] = racc[(cbl + m) * 68 + r0];
            float* dst = S + (long)cc0 * C + rb + cbl;
            *reinterpret_cast<float2*>(dst) = make_float2(wv[0], wv[1]);
            *reinterpret_cast<float2*>(dst + 2) = make_float2(wv[2], wv[3]);
        }
    }
}

// per-row: best/argmax (excl diag) of cos values + global min/max (incl diag).
__global__ void k_rowmax(const float* S, const float* norms, unsigned* minmax,
                         float* simraw, int* simcls, int C) {
    __shared__ float invn[1024];
    __shared__ float rv[256], rmn[256], rmx[256];
    __shared__ int ri[256];
    int c = blockIdx.x, t = threadIdx.x;
    for (int j = t; j < C; j += 256) invn[j] = 1.f / norms[j];
    __syncthreads();
    float inc = invn[c];
    float best = -INFINITY, lmin = INFINITY, lmax = -INFINITY;
    int bi = 0x7FFFFFFF;
    long rowo = (long)c * C;
    for (int j = t; j < C; j += 256) {
        float v = S[rowo + j] * inc * invn[j];
        lmin = fminf(lmin, v);
        lmax = fmaxf(lmax, v);
        if (j != c && v > best) { best = v; bi = j; }
    }
    rv[t] = best; ri[t] = bi; rmn[t] = lmin; rmx[t] = lmax;
    __syncthreads();
    for (int k = 128; k > 0; k >>= 1) {
        if (t < k) {
            if (rv[t + k] > rv[t] || (rv[t + k] == rv[t] && ri[t + k] < ri[t])) {
                rv[t] = rv[t + k];
                ri[t] = ri[t + k];
            }
            rmn[t] = fminf(rmn[t], rmn[t + k]);
            rmx[t] = fmaxf(rmx[t], rmx[t + k]);
        }
        __syncthreads();
    }
    if (t == 0) {
        simraw[c] = rv[0];
        simcls[c] = ri[0];
        atomicMin(&minmax[0], fenc(rmn[0]));
        atomicMax(&minmax[1], fenc(rmx[0]));
    }
}

// feature loss: wave per sample, 4 samples/block.
__global__ __launch_bounds__(256) void k_floss(
        const float* feat, const float* ftab, const float* norms, const int* tgt,
        const unsigned* minmax, const float* simraw, const int* simcls,
        float* fpart, int B, int D) {
    int wid = threadIdx.x >> 6, lane = threadIdx.x & 63;
    int s = blockIdx.x * 4 + wid;
    int cls = tgt[s];
    int sc = simcls[cls];
    const float4* f4 = (const float4*)(feat + (long)s * D);
    const float2* ft2 = (const float2*)(ftab + (long)cls * D);
    const float2* fs2 = (const float2*)(ftab + (long)sc * D);
    float d1 = 0.f, d2 = 0.f, nf2 = 0.f;
#pragma unroll
    for (int i = 0; i < 4; i++) {
        int j = lane + i * 64;
        float4 x = f4[j];
        float2 a0 = ft2[2 * j], a1 = ft2[2 * j + 1];
        float2 b0 = fs2[2 * j], b1 = fs2[2 * j + 1];
        d1 += x.x * a0.x + x.y * a0.y + x.z * a1.x + x.w * a1.y;
        d2 += x.x * b0.x + x.y * b0.y + x.z * b1.x + x.w * b1.y;
        nf2 += x.x * x.x + x.y * x.y + x.z * x.z + x.w * x.w;
    }
    for (int o = 32; o > 0; o >>= 1) {
        d1 += __shfl_down(d1, o);
        d2 += __shfl_down(d2, o);
        nf2 += __shfl_down(nf2, o);
    }
    __shared__ float part[4];
    if (lane == 0) {
        float cmin = fdec(minmax[0]);
        float cmax = fdec(minmax[1]);
        float sv = (simraw[cls] - cmin) / (cmax - cmin);
        float nf = fmaxf(sqrtf(nf2), EPS);
        float nt = fmaxf(norms[cls], EPS);
        float ns = fmaxf(norms[sc], EPS);
        part[wid] = (1.f - d1 / (nf * nt)) + (d2 / (nf * ns)) * sv;
    }
    __syncthreads();
    if (threadIdx.x == 0) fpart[blockIdx.x] = part[0] + part[1] + part[2] + part[3];
}

__global__ void k_final(const float* fpart, const float* klpart, float* out, int nf, int nk) {
    __shared__ float red[256];
    float a = 0.f;
    for (int i = threadIdx.x; i < nf; i += 256) a += fpart[i];
    a = block_sum(a, red);
    float b = 0.f;
    for (int i = threadIdx.x; i < nk; i += 256) b += klpart[i];
    b = block_sum(b, red);
    if (threadIdx.x == 0) {
        out[0] = a;
        out[1] = b;
    }
}

extern "C" void kernel_launch(void* const* d_in, const int* in_sizes, int n_in,
                              void* d_out, int out_size, void* d_ws, size_t ws_size,
                              hipStream_t stream) {
    const float* feature = (const float*)d_in[0];
    const float* logits  = (const float*)d_in[1];
    const int*   targets = (const int*)d_in[2];
    const float* finit   = (const float*)d_in[3];
    const float* linit   = (const float*)d_in[4];

    const int B = in_sizes[2];                 // 16384
    const int D = in_sizes[0] / B;             // 1024
    const int C = in_sizes[3] / D;             // 1000

    float* out = (float*)d_out;
    float* ftab = out + 2;                     // [C, D]
    float* ltab = out + 2 + (long)C * D;       // [C, C]

    const int G = (B + 255) / 256;             // 64 groups
    const int NT = (C + 63) / 64;              // 16 tiles per dim
    const int NTRI = NT * (NT + 1) / 2;        // 136 triangular tiles

    char* ws = (char*)d_ws;
    int*      counts  = (int*)(ws + 0);        // 1024
    int*      offsets = (int*)(ws + 4096);     // 1024
    int*      idx     = (int*)(ws + 12288);    // 16384
    float*    norms   = (float*)(ws + 77824);  // 1024
    float*    simraw  = (float*)(ws + 81920);  // 1024
    int*      simcls  = (int*)(ws + 86016);    // 1024
    unsigned* minmax  = (unsigned*)(ws + 90112); // 2
    float*    fpart   = (float*)(ws + 90368);  // 4096
    float*    klpart  = (float*)(ws + 106752); // 16384
    float*    Sws     = (float*)(ws + 262144); // C*C floats (S scratch)

    int sInWs = (ws_size >= 262144 + (size_t)C * C * sizeof(float)) ? 1 : 0;
    float* S = sInWs ? Sws : ltab;

    // gh scratch lives in the (not-yet-written) ltab output region
    int* gh = (int*)ltab;

    k_ghist<<<G, 256, 0, stream>>>(targets, gh, B);
    k_bases<<<1, 1024, 0, stream>>>(gh, counts, offsets, minmax, G, C);
    k_rank_scatter<<<G, 256, 0, stream>>>(targets, offsets, gh, idx, B);

    const int KB16 = B / 16;                   // 1024 KL blocks (16 samples each)
    if (sInWs) {
        // both gathers in one dispatch (gather wall aggregates)
        k_tables<<<2 * C, 256, 0, stream>>>(feature, finit, logits, linit,
                                            counts, offsets, idx, ftab, ltab, norms, C, D, C);
        // GEMM (needs ftab) fused with KL (needs ltab): GEMM hides under KL
        k_gemm_kl<<<NTRI + KB16, 1024, 0, stream>>>(ftab, S, logits, ltab, targets,
                                                    klpart, C, D, NT, NTRI, C);
        k_rowmax<<<C, 256, 0, stream>>>(S, norms, minmax, simraw, simcls, C);
    } else {
        // fallback: S in ltab region -> serialize: ftab, gemm, rowmax, both tables, KL
        k_tables<<<C, 256, 0, stream>>>(feature, finit, logits, linit,
                                        counts, offsets, idx, ftab, ltab, norms, C, D, C);
        k_gemm_kl<<<NTRI, 1024, 0, stream>>>(ftab, S, logits, ltab, targets,
                                             klpart, C, D, NT, NTRI, C);
        k_rowmax<<<C, 256, 0, stream>>>(S, norms, minmax, simraw, simcls, C);
        k_tables<<<2 * C, 256, 0, stream>>>(feature, finit, logits, linit,
                                            counts, offsets, idx, ftab, ltab, norms, C, D, C);
        k_gemm_kl<<<KB16, 1024, 0, stream>>>(ftab, S, logits, ltab, targets,
                                             klpart, C, D, NT, 0 /*KL only*/, C);
    }

    k_floss<<<B / 4, 256, 0, stream>>>(feature, ftab, norms, targets, minmax, simraw,
                                       simcls, fpart, B, D);
    k_final<<<1, 256, 0, stream>>>(fpart, klpart, out, B / 4, B);
}

// Round 27
// 133.215 us; speedup vs baseline: 1.1748x; 1.1748x over previous
//
#include <hip/hip_runtime.h>
#include <hip/hip_bf16.h>
#include <math.h>

#define EPS 1e-8f

typedef __attribute__((ext_vector_type(8))) short short8v;
typedef __attribute__((ext_vector_type(4))) float f32x4;

// ---------- helpers ----------
__device__ __forceinline__ unsigned fenc(float f) {
    unsigned u = __float_as_uint(f);
    return (u & 0x80000000u) ? ~u : (u | 0x80000000u);
}
__device__ __forceinline__ float fdec(unsigned e) {
    unsigned u = (e & 0x80000000u) ? (e & 0x7FFFFFFFu) : ~e;
    return __uint_as_float(u);
}
__device__ __forceinline__ unsigned short f2bf(float f) {   // RNE f32 -> bf16
    unsigned u = __float_as_uint(f);
    u += 0x7FFFu + ((u >> 16) & 1u);
    return (unsigned short)(u >> 16);
}

__device__ __forceinline__ float block_sum(float v, float* red) {
    red[threadIdx.x] = v;
    __syncthreads();
    for (int k = 128; k > 0; k >>= 1) {
        if (threadIdx.x < k) red[threadIdx.x] += red[threadIdx.x + k];
        __syncthreads();
    }
    float r = red[0];
    __syncthreads();
    return r;
}
__device__ __forceinline__ float block_max(float v, float* red) {
    red[threadIdx.x] = v;
    __syncthreads();
    for (int k = 128; k > 0; k >>= 1) {
        if (threadIdx.x < k) red[threadIdx.x] = fmaxf(red[threadIdx.x], red[threadIdx.x + k]);
        __syncthreads();
    }
    float r = red[0];
    __syncthreads();
    return r;
}

// ---------- kernels ----------
// FUSED prepass: blocks [0,64) = target histogram; blocks [64,64+B/4) = per-row
// 1/max(||f||,eps); blocks [64+B/4, 64+B/2) = per-row logsumexp(logits).
// Streams both inputs coalesced (also warms L3 for the later gather).
__global__ __launch_bounds__(256) void k_pre(const int* tgt, int* gh,
                                             const float* feat, float* fnorminv,
                                             const float* logits, float* lse,
                                             int B, int D, int C2) {
    __shared__ int lh[1024];
    int t = threadIdx.x;
    int bid = blockIdx.x;
    if (bid < 64) {
        int g = bid;
        lh[t] = 0; lh[t + 256] = 0; lh[t + 512] = 0; lh[t + 768] = 0;
        __syncthreads();
        int base = g * 256;
        for (int i = base + t; i < B; i += 64 * 256) atomicAdd(&lh[tgt[i]], 1);
        __syncthreads();
        int* dst = gh + g * 1024;
        dst[t] = lh[t]; dst[t + 256] = lh[t + 256];
        dst[t + 512] = lh[t + 512]; dst[t + 768] = lh[t + 768];
        return;
    }
    int wid = t >> 6, lane = t & 63;
    int nf = B / 4;
    if (bid < 64 + nf) {
        // per-row feature inverse norm (wave per row)
        int row = (bid - 64) * 4 + wid;
        const float4* f4 = (const float4*)(feat + (long)row * D);
        float ss = 0.f;
#pragma unroll
        for (int k = 0; k < 4; k++) {
            float4 v = f4[lane + 64 * k];
            ss += v.x * v.x + v.y * v.y + v.z * v.z + v.w * v.w;
        }
#pragma unroll
        for (int o = 32; o > 0; o >>= 1) ss += __shfl_xor(ss, o);
        if (lane == 0) fnorminv[row] = 1.f / fmaxf(sqrtf(ss), EPS);
    } else {
        // per-row logsumexp of logits (wave per row)
        int row = (bid - 64 - nf) * 4 + wid;
        const float4* l4 = (const float4*)(logits + (long)row * C2);
        int Q = C2 >> 2;    // 250
        float ta[16];
        float m = -INFINITY;
#pragma unroll
        for (int k = 0; k < 4; k++) {
            int j = lane + 64 * k;
            if (j < Q) {
                float4 v = l4[j];
                ta[4 * k] = v.x; ta[4 * k + 1] = v.y; ta[4 * k + 2] = v.z; ta[4 * k + 3] = v.w;
                m = fmaxf(m, fmaxf(fmaxf(v.x, v.y), fmaxf(v.z, v.w)));
            } else {
#pragma unroll
                for (int r = 0; r < 4; r++) ta[4 * k + r] = -INFINITY;
            }
        }
#pragma unroll
        for (int o = 32; o > 0; o >>= 1) m = fmaxf(m, __shfl_xor(m, o));
        float s = 0.f;
#pragma unroll
        for (int i = 0; i < 16; i++)
            if (ta[i] != -INFINITY) s += __expf(ta[i] - m);
#pragma unroll
        for (int o = 32; o > 0; o >>= 1) s += __shfl_xor(s, o);
        if (lane == 0) lse[row] = m + __logf(s);
    }
}

__global__ void k_bases(int* gh, int* counts, int* offsets, unsigned* minmax, int G, int C) {
    __shared__ int buf[1024];
    int c = threadIdx.x;
    if (c == 0) { minmax[0] = 0xFFFFFFFFu; minmax[1] = 0u; }
    int run = 0;
#pragma unroll 16
    for (int g = 0; g < G; g++) {
        int v = gh[g * 1024 + c];
        gh[g * 1024 + c] = run;
        run += v;
    }
    if (c < C) counts[c] = run;
    int v0 = (c < C) ? run : 0;
    buf[c] = v0;
    __syncthreads();
    for (int off = 1; off < 1024; off <<= 1) {
        int v = (c >= off) ? buf[c - off] : 0;
        __syncthreads();
        buf[c] += v;
        __syncthreads();
    }
    if (c < C) offsets[c] = buf[c] - v0;
}

__global__ void k_rank_scatter(const int* tgt, const int* offsets, const int* gh,
                               int* idx, int B) {
    __shared__ int lt[256];
    int g = blockIdx.x, t = threadIdx.x;
    int i = g * 256 + t;
    int my = (i < B) ? tgt[i] : -1;
    lt[t] = my;
    __syncthreads();
    if (i < B) {
        int rank = 0;
        for (int j = 0; j < t; j++) rank += (lt[j] == my);
        idx[offsets[my] + gh[g * 1024 + my] + rank] = i;
    }
}

// FUSED table build: blocks [0,C) -> feature table + norms + g = sum of normalized
// rows; blocks [C,2C) -> logit table. Register idx + __shfl broadcast; deterministic.
__global__ __launch_bounds__(256) void k_tables(const float* feat, const float* finit,
                                                const float* logits, const float* linit,
                                                const int* counts, const int* offsets,
                                                const int* idx, const float* fnorminv,
                                                float* ftab, float* ltab, float* norms,
                                                float* gsum,
                                                int C, int D, int C2) {
    __shared__ float red[256];
    int t = threadIdx.x;
    int lane = t & 63;
    if ((int)blockIdx.x < C) {
        int c = blockIdx.x;
        int n = counts[c];
        float o0, o1, o2, o3;
        float4 acc2 = {0.f, 0.f, 0.f, 0.f};
        if (n == 0) {
            float4 v = ((const float4*)(finit + (long)c * D))[t];
            o0 = v.x; o1 = v.y; o2 = v.z; o3 = v.w;
        } else {
            const float4* base4 = (const float4*)feat;
            int rowq = D >> 2;
            int o = offsets[c];
            float4 acc = {0.f, 0.f, 0.f, 0.f};
            for (int base = 0; base < n; base += 64) {
                int m = min(64, n - base);
                int lid = idx[o + base + min(lane, m - 1)];
                float fvl = fnorminv[lid];
                int m4 = m & ~3;
                int j = 0;
                for (; j < m4; j += 4) {
                    int i0 = __shfl(lid, j);
                    int i1 = __shfl(lid, j + 1);
                    int i2 = __shfl(lid, j + 2);
                    int i3 = __shfl(lid, j + 3);
                    float f0 = __shfl(fvl, j);
                    float f1 = __shfl(fvl, j + 1);
                    float f2 = __shfl(fvl, j + 2);
                    float f3 = __shfl(fvl, j + 3);
                    float4 v0 = base4[(long)i0 * rowq + t];
                    float4 v1 = base4[(long)i1 * rowq + t];
                    float4 v2 = base4[(long)i2 * rowq + t];
                    float4 v3 = base4[(long)i3 * rowq + t];
                    acc.x += v0.x; acc.y += v0.y; acc.z += v0.z; acc.w += v0.w;
                    acc2.x += v0.x * f0; acc2.y += v0.y * f0; acc2.z += v0.z * f0; acc2.w += v0.w * f0;
                    acc.x += v1.x; acc.y += v1.y; acc.z += v1.z; acc.w += v1.w;
                    acc2.x += v1.x * f1; acc2.y += v1.y * f1; acc2.z += v1.z * f1; acc2.w += v1.w * f1;
                    acc.x += v2.x; acc.y += v2.y; acc.z += v2.z; acc.w += v2.w;
                    acc2.x += v2.x * f2; acc2.y += v2.y * f2; acc2.z += v2.z * f2; acc2.w += v2.w * f2;
                    acc.x += v3.x; acc.y += v3.y; acc.z += v3.z; acc.w += v3.w;
                    acc2.x += v3.x * f3; acc2.y += v3.y * f3; acc2.z += v3.z * f3; acc2.w += v3.w * f3;
                }
                for (; j < m; j++) {
                    int i0 = __shfl(lid, j);
                    float f0 = __shfl(fvl, j);
                    float4 v0 = base4[(long)i0 * rowq + t];
                    acc.x += v0.x; acc.y += v0.y; acc.z += v0.z; acc.w += v0.w;
                    acc2.x += v0.x * f0; acc2.y += v0.y * f0; acc2.z += v0.z * f0; acc2.w += v0.w * f0;
                }
            }
            float inv = 1.0f / (float)n;
            o0 = acc.x * inv; o1 = acc.y * inv; o2 = acc.z * inv; o3 = acc.w * inv;
        }
        float* dst = ftab + (long)c * D + t * 4;
        dst[0] = o0; dst[1] = o1; dst[2] = o2; dst[3] = o3;
        if (n > 0) ((float4*)(gsum + (long)c * D))[t] = acc2;
        float ss = o0 * o0 + o1 * o1 + o2 * o2 + o3 * o3;
        ss = block_sum(ss, red);
        if (t == 0) norms[c] = sqrtf(ss);
    } else {
        int c = blockIdx.x - C;
        int n = counts[c];
        int nv = C2 >> 2;                           // 250
        if (n == 0) {
            for (int d = t; d < C2; d += 256) ltab[(long)c * C2 + d] = linit[(long)c * C2 + d];
            return;
        }
        int tc = min(t, nv - 1);
        int o = offsets[c];
        float4 acc = {0.f, 0.f, 0.f, 0.f};
        for (int base = 0; base < n; base += 64) {
            int m = min(64, n - base);
            int lid = idx[o + base + min(lane, m - 1)];
            int m4 = m & ~3;
            int j = 0;
            for (; j < m4; j += 4) {
                int i0 = __shfl(lid, j);
                int i1 = __shfl(lid, j + 1);
                int i2 = __shfl(lid, j + 2);
                int i3 = __shfl(lid, j + 3);
                float4 v0 = *(const float4*)(logits + (long)i0 * C2 + tc * 4);
                float4 v1 = *(const float4*)(logits + (long)i1 * C2 + tc * 4);
                float4 v2 = *(const float4*)(logits + (long)i2 * C2 + tc * 4);
                float4 v3 = *(const float4*)(logits + (long)i3 * C2 + tc * 4);
                acc.x += v0.x; acc.y += v0.y; acc.z += v0.z; acc.w += v0.w;
                acc.x += v1.x; acc.y += v1.y; acc.z += v1.z; acc.w += v1.w;
                acc.x += v2.x; acc.y += v2.y; acc.z += v2.z; acc.w += v2.w;
                acc.x += v3.x; acc.y += v3.y; acc.z += v3.z; acc.w += v3.w;
            }
            for (; j < m; j++) {
                int i0 = __shfl(lid, j);
                float4 v0 = *(const float4*)(logits + (long)i0 * C2 + tc * 4);
                acc.x += v0.x; acc.y += v0.y; acc.z += v0.z; acc.w += v0.w;
            }
        }
        if (t < nv) {
            float inv = 1.0f / (float)n;
            float* dst = ltab + (long)c * C2 + t * 4;
            dst[0] = acc.x * inv;
            dst[1] = acc.y * inv;
            dst[2] = acc.z * inv;
            dst[3] = acc.w * inv;
        }
    }
}

// Triangular raw-dot GEMM via bf16 MFMA (verified r23/r24): one block per tile.
__global__ __launch_bounds__(1024) void k_gemm(const float* A, float* S,
                                               int C, int D, int NT) {
    __shared__ __align__(16) unsigned short As[2][64][40];
    __shared__ __align__(16) unsigned short Bs[2][64][40];
    __shared__ __align__(16) float racc[64 * 68];
    int t = threadIdx.x;

    int q = blockIdx.x, ti = 0;
    while (q >= NT - ti) { q -= NT - ti; ti++; }
    int tj = ti + q;
    int rb = ti * 64, cb = tj * 64;

    int srow = t >> 4;
    int skq = (t & 15) * 2;
    int ga = rb + srow, gb = cb + srow;
    bool okA = ga < C, okB = gb < C;
    const float* arow = A + (long)ga * D;
    const float* brow = A + (long)gb * D;

    int w = t >> 6, wr = w >> 2, wc = w & 3;
    int l = t & 63, fr = l & 15, fb = l >> 4;
    int arl = wr * 16 + fr, brl = wc * 16 + fr, koff = fb * 8;

    {
        float2 z2 = {0.f, 0.f};
        float2 pa = okA ? *(const float2*)(arow + skq) : z2;
        float2 pb = okB ? *(const float2*)(brow + skq) : z2;
        As[0][srow][skq] = f2bf(pa.x); As[0][srow][skq + 1] = f2bf(pa.y);
        Bs[0][srow][skq] = f2bf(pb.x); Bs[0][srow][skq + 1] = f2bf(pb.y);
    }
    __syncthreads();

    f32x4 acc = {0.f, 0.f, 0.f, 0.f};
    int nsteps = D >> 5;               // 32
    for (int step = 0; step < nsteps; step++) {
        int cur = step & 1;
        float2 pa, pb;
        if (step < nsteps - 1) {
            int k0n = (step + 1) * 32;
            float2 z2 = {0.f, 0.f};
            pa = okA ? *(const float2*)(arow + k0n + skq) : z2;
            pb = okB ? *(const float2*)(brow + k0n + skq) : z2;
        }
        short8v af = *reinterpret_cast<const short8v*>(&As[cur][arl][koff]);
        short8v bf = *reinterpret_cast<const short8v*>(&Bs[cur][brl][koff]);
        acc = __builtin_amdgcn_mfma_f32_16x16x32_bf16(af, bf, acc, 0, 0, 0);
        if (step < nsteps - 1) {
            int nb = cur ^ 1;
            As[nb][srow][skq] = f2bf(pa.x); As[nb][srow][skq + 1] = f2bf(pa.y);
            Bs[nb][srow][skq] = f2bf(pb.x); Bs[nb][srow][skq + 1] = f2bf(pb.y);
        }
        __syncthreads();
    }

#pragma unroll
    for (int r = 0; r < 4; r++)
        racc[(wr * 16 + fb * 4 + r) * 68 + wc * 16 + fr] = acc[r];
    __syncthreads();

    int r0 = t >> 4;
    int cbl = (t & 15) * 4;
    int gr = rb + r0;
    bool edge = (tj == NT - 1);
    if (gr < C) {
        float4 v4 = *reinterpret_cast<const float4*>(&racc[r0 * 68 + cbl]);
        float v[4] = {v4.x, v4.y, v4.z, v4.w};
        float* dst = S + (long)gr * C + cb + cbl;
        if (!edge) {
            *reinterpret_cast<float2*>(dst) = make_float2(v[0], v[1]);
            *reinterpret_cast<float2*>(dst + 2) = make_float2(v[2], v[3]);
        } else {
#pragma unroll
            for (int m = 0; m < 4; m++)
                if (cb + cbl + m < C) dst[m] = v[m];
        }
    }
    if (ti != tj) {
        int cc0 = cb + r0;
        if (cc0 < C) {
            float wv[4];
#pragma unroll
            for (int m = 0; m < 4; m++) wv[m] = racc[(cbl + m) * 68 + r0];
            float* dst = S + (long)cc0 * C + rb + cbl;
            *reinterpret_cast<float2*>(dst) = make_float2(wv[0], wv[1]);
            *reinterpret_cast<float2*>(dst + 2) = make_float2(wv[2], wv[3]);
        }
    }
}

// per-row: best/argmax (excl diag) of cos values + global min/max (incl diag).
__global__ void k_rowmax(const float* S, const float* norms, unsigned* minmax,
                         float* simraw, int* simcls, int C) {
    __shared__ float invn[1024];
    __shared__ float rv[256], rmn[256], rmx[256];
    __shared__ int ri[256];
    int c = blockIdx.x, t = threadIdx.x;
    for (int j = t; j < C; j += 256) invn[j] = 1.f / norms[j];
    __syncthreads();
    float inc = invn[c];
    float best = -INFINITY, lmin = INFINITY, lmax = -INFINITY;
    int bi = 0x7FFFFFFF;
    long rowo = (long)c * C;
    for (int j = t; j < C; j += 256) {
        float v = S[rowo + j] * inc * invn[j];
        lmin = fminf(lmin, v);
        lmax = fmaxf(lmax, v);
        if (j != c && v > best) { best = v; bi = j; }
    }
    rv[t] = best; ri[t] = bi; rmn[t] = lmin; rmx[t] = lmax;
    __syncthreads();
    for (int k = 128; k > 0; k >>= 1) {
        if (t < k) {
            if (rv[t + k] > rv[t] || (rv[t + k] == rv[t] && ri[t + k] < ri[t])) {
                rv[t] = rv[t + k];
                ri[t] = ri[t + k];
            }
            rmn[t] = fminf(rmn[t], rmn[t + k]);
            rmx[t] = fmaxf(rmx[t], rmx[t + k]);
        }
        __syncthreads();
    }
    if (t == 0) {
        simraw[c] = rv[0];
        simcls[c] = ri[0];
        atomicMin(&minmax[0], fenc(rmn[0]));
        atomicMax(&minmax[1], fenc(rmx[0]));
    }
}

// Per-class losses via factored identities:
//  cpf[c] = n_c - dot(g_c,u_c)/max(|u_c|,eps) + sv_c*dot(g_c,v_c)/max(|v_c|,eps)
//  cpk[c] = LSE_c - n_c*lse(ltab_c)
__global__ __launch_bounds__(256) void k_closs(const float* gsum, const float* ftab,
                                               const float* norms, const int* counts,
                                               const int* offsets, const int* idx,
                                               const float* lse, const float* ltab,
                                               const unsigned* minmax, const float* simraw,
                                               const int* simcls,
                                               float* cpf, float* cpk,
                                               int C, int D, int C2) {
    __shared__ float red[256];
    int c = blockIdx.x, t = threadIdx.x;
    int n = counts[c];
    if (n == 0) {
        if (t == 0) { cpf[c] = 0.f; cpk[c] = 0.f; }
        return;
    }
    int sc = simcls[c];
    // d1 = g.u, d2 = g.v  (g 16B-aligned; ftab rows 8B-aligned -> scalar loads)
    float4 g4 = ((const float4*)(gsum + (long)c * D))[t];
    const float* u = ftab + (long)c * D + t * 4;
    const float* v = ftab + (long)sc * D + t * 4;
    float d1 = g4.x * u[0] + g4.y * u[1] + g4.z * u[2] + g4.w * u[3];
    float d2 = g4.x * v[0] + g4.y * v[1] + g4.z * v[2] + g4.w * v[3];
    d1 = block_sum(d1, red);
    d2 = block_sum(d2, red);
    // lse of ltab row c (1000 floats)
    float ta[4];
    float lm = -INFINITY;
#pragma unroll
    for (int k = 0; k < 4; k++) {
        int j = t + k * 256;
        if (j < C2) { ta[k] = ltab[(long)c * C2 + j]; lm = fmaxf(lm, ta[k]); }
        else ta[k] = -INFINITY;
    }
    lm = block_max(lm, red);
    float se = 0.f;
#pragma unroll
    for (int k = 0; k < 4; k++)
        if (ta[k] != -INFINITY) se += __expf(ta[k] - lm);
    se = block_sum(se, red);
    // LSE_c = sum of per-sample lse over this class
    float ls = 0.f;
    int o = offsets[c];
    for (int i = t; i < n; i += 256) ls += lse[idx[o + i]];
    ls = block_sum(ls, red);
    if (t == 0) {
        float cmin = fdec(minmax[0]);
        float cmax = fdec(minmax[1]);
        float sv = (simraw[c] - cmin) / (cmax - cmin);
        float nu = fmaxf(norms[c], EPS);
        float nv = fmaxf(norms[sc], EPS);
        cpf[c] = (float)n - d1 / nu + sv * d2 / nv;
        cpk[c] = ls - (float)n * (lm + __logf(se));
    }
}

__global__ void k_final(const float* cpf, const float* cpk, float* out, int C) {
    __shared__ float red[256];
    float a = 0.f;
    for (int i = threadIdx.x; i < C; i += 256) a += cpf[i];
    a = block_sum(a, red);
    float b = 0.f;
    for (int i = threadIdx.x; i < C; i += 256) b += cpk[i];
    b = block_sum(b, red);
    if (threadIdx.x == 0) {
        out[0] = a;
        out[1] = b;
    }
}

extern "C" void kernel_launch(void* const* d_in, const int* in_sizes, int n_in,
                              void* d_out, int out_size, void* d_ws, size_t ws_size,
                              hipStream_t stream) {
    const float* feature = (const float*)d_in[0];
    const float* logits  = (const float*)d_in[1];
    const int*   targets = (const int*)d_in[2];
    const float* finit   = (const float*)d_in[3];
    const float* linit   = (const float*)d_in[4];

    const int B = in_sizes[2];                 // 16384
    const int D = in_sizes[0] / B;             // 1024
    const int C = in_sizes[3] / D;             // 1000

    float* out = (float*)d_out;
    float* ftab = out + 2;                     // [C, D]
    float* ltab = out + 2 + (long)C * D;       // [C, C]

    const int G = 64;                          // histogram groups
    const int NT = (C + 63) / 64;              // 16 tiles per dim
    const int NTRI = NT * (NT + 1) / 2;        // 136 triangular tiles

    char* ws = (char*)d_ws;
    int*      counts   = (int*)(ws + 0);          // 4KB
    int*      offsets  = (int*)(ws + 4096);       // 4KB
    int*      idx      = (int*)(ws + 12288);      // 64KB
    float*    norms    = (float*)(ws + 77824);    // 4KB
    float*    simraw   = (float*)(ws + 81920);    // 4KB
    int*      simcls   = (int*)(ws + 86016);      // 4KB
    unsigned* minmax   = (unsigned*)(ws + 90112); // 8B
    float*    cpf      = (float*)(ws + 90368);    // 4KB
    float*    cpk      = (float*)(ws + 94464);    // 4KB
    float*    fnorminv = (float*)(ws + 98560);    // 64KB
    float*    lse      = (float*)(ws + 164096);   // 64KB
    float*    Sws      = (float*)(ws + 262144);   // C*C floats = 4MB
    float*    gsum     = (float*)(ws + 262144 + (size_t)C * C * sizeof(float)); // C*D = 4.1MB

    float* S = Sws;                            // ws_size >= 12.25MB proven (round 12)

    // gh scratch lives in the (not-yet-written) ltab output region
    int* gh = (int*)ltab;

    // prepass: histogram + per-row 1/|f| + per-row lse (streams both inputs)
    k_pre<<<64 + B / 2, 256, 0, stream>>>(targets, gh, feature, fnorminv,
                                          logits, lse, B, D, C);
    k_bases<<<1, 1024, 0, stream>>>(gh, counts, offsets, minmax, G, C);
    k_rank_scatter<<<G, 256, 0, stream>>>(targets, offsets, gh, idx, B);

    // both gathers in one dispatch; feature path also accumulates g = sum(f/|f|)
    k_tables<<<2 * C, 256, 0, stream>>>(feature, finit, logits, linit,
                                        counts, offsets, idx, fnorminv,
                                        ftab, ltab, norms, gsum, C, D, C);

    k_gemm<<<NTRI, 1024, 0, stream>>>(ftab, S, C, D, NT);
    k_rowmax<<<C, 256, 0, stream>>>(S, norms, minmax, simraw, simcls, C);
    k_closs<<<C, 256, 0, stream>>>(gsum, ftab, norms, counts, offsets, idx,
                                   lse, ltab, minmax, simraw, simcls, cpf, cpk, C, D, C);
    k_final<<<1, 256, 0, stream>>>(cpf, cpk, out, C);
}